// Round 2
// baseline (9437.289 us; speedup 1.0000x reference)
//
#include <hip/hip_runtime.h>

typedef unsigned short u16;
typedef __bf16 bf16x8 __attribute__((ext_vector_type(8)));
typedef float f32x4 __attribute__((ext_vector_type(4)));

#define N_NODES 100000
#define D 256
#define NLAYER 4
#define E2N 300000
#define E3N 200000
#define TGT 2000

__device__ __forceinline__ u16 f2b(float f) {
    union { float f; unsigned u; } v; v.f = f;
    unsigned r = v.u + 0x7FFFu + ((v.u >> 16) & 1u);
    return (u16)(r >> 16);
}
__device__ __forceinline__ float b2f(u16 u) {
    union { unsigned u; float f; } v; v.u = ((unsigned)u) << 16; return v.f;
}

// ---------------- embedding gather ----------------
__global__ __launch_bounds__(256)
void embed_kernel(const int* __restrict__ x, const float* __restrict__ emb,
                  u16* __restrict__ hb, int n) {
    int wid = threadIdx.x >> 6, lane = threadIdx.x & 63;
    int row = blockIdx.x * 4 + wid;
    if (row >= n) return;
    int v = x[row];
    float4 f = *(const float4*)(emb + v * D + lane * 4);
    ushort4 o; o.x = f2b(f.x); o.y = f2b(f.y); o.z = f2b(f.z); o.w = f2b(f.w);
    *(ushort4*)(hb + row * D + lane * 4) = o;
}

// ---------------- W (L,K,N) f32 -> Wt (L,N,K) bf16 ----------------
__global__ __launch_bounds__(256)
void convert_wt(const float* __restrict__ W, u16* __restrict__ Wt,
                int total, int K, int N) {
    int idx = blockIdx.x * 256 + threadIdx.x;
    if (idx >= total) return;
    int kk = idx % K;
    int rem = idx / K;
    int nn = rem % N;
    int l  = rem / N;
    Wt[idx] = f2b(W[(l * K + kk) * N + nn]);
}

// ---------------- counting sort of (type,slot) edge entries by dest ----------------
#define NBINS 100000
#define NSEG 5              // e2:s0, e2:s1, e3:s0, e3:s1, e3:s2
#define TOTENT 1200000

__global__ __launch_bounds__(256)
void zero_counts(int* __restrict__ counts) {
    int i = blockIdx.x * 256 + threadIdx.x;
    if (i < NSEG * NBINS) counts[i] = 0;
}

__device__ __forceinline__ void decode_entry(int i, const int* e2, const int* e3,
                                             int& seg, int& key, int& e, int& is2) {
    if (i < 2 * E2N) {
        int s = i / E2N; e = i - s * E2N;
        seg = s; key = e2[s * E2N + e]; is2 = 1;
    } else {
        int j = i - 2 * E2N; int s = j / E3N; e = j - s * E3N;
        seg = 2 + s; key = e3[s * E3N + e]; is2 = 0;
    }
}

__global__ __launch_bounds__(256)
void hist_kernel(const int* __restrict__ e2, const int* __restrict__ e3,
                 int* __restrict__ counts) {
    int i = blockIdx.x * 256 + threadIdx.x;
    if (i >= TOTENT) return;
    int seg, key, e, is2;
    decode_entry(i, e2, e3, seg, key, e, is2);
    atomicAdd(counts + seg * NBINS + key, 1);
}

__global__ __launch_bounds__(1024)
void scan_kernel(int* __restrict__ counts) {   // grid = NSEG blocks
    __shared__ int ps[1024];
    int* seg = counts + blockIdx.x * NBINS;
    int t = threadIdx.x;
    const int C = (NBINS + 1023) / 1024;       // 98
    int b = t * C, en = b + C; if (en > NBINS) en = NBINS; if (b > NBINS) b = NBINS;
    int s = 0;
    for (int i = b; i < en; ++i) s += seg[i];
    ps[t] = s; __syncthreads();
    for (int off = 1; off < 1024; off <<= 1) {
        int v = ps[t];
        if (t >= off) v += ps[t - off];
        __syncthreads();
        ps[t] = v; __syncthreads();
    }
    int run = (t == 0) ? 0 : ps[t - 1];
    for (int i = b; i < en; ++i) { int c = seg[i]; seg[i] = run; run += c; }
}

__global__ __launch_bounds__(256)
void scatter_kernel(const int* __restrict__ e2, const int* __restrict__ e3,
                    int* __restrict__ counts, int* __restrict__ sorted2,
                    int* __restrict__ sorted3) {
    int i = blockIdx.x * 256 + threadIdx.x;
    if (i >= TOTENT) return;
    int seg, key, e, is2;
    decode_entry(i, e2, e3, seg, key, e, is2);
    int pos = atomicAdd(counts + seg * NBINS + key, 1);
    if (is2) sorted2[seg * E2N + pos] = e;
    else     sorted3[(seg - 2) * E3N + pos] = e;
}

// ---------------- fused gather-GEMM-sorted-scatter ----------------
// One 256-col output slot per launch. BM=64, BN=256, K = arity*256.
// A[e,k] = hb[eidx[k/256][sorted[e]]][k%256]; C scattered by eidx[slot][sorted[e]].
#define BM 64
#define BN 256
#define BK 64
#define LDSP 144
#define BOFF 9216          // 64*144

template<int ARITY>
__global__ __launch_bounds__(256)
void gemm_scatter(const u16* __restrict__ hb, const u16* __restrict__ Wt,
                  const int* __restrict__ eidx, const int* __restrict__ sorted,
                  int slot, float* __restrict__ agg, int E) {
    constexpr int KT = (ARITY == 0 ? 1 : ARITY) * 256;
    constexpr int NR = (ARITY == 0 ? 1 : ARITY);
    __shared__ __align__(16) char smem[(64 + 256) * LDSP];

    const int m0 = blockIdx.x * BM;
    const int tid = threadIdx.x;
    const int lane = tid & 63;
    const int wid = tid >> 6;
    const int wn = wid * 64;
    const int srow = tid >> 3;   // 0..31
    const int sc   = tid & 7;    // 16B chunk

    f32x4 acc[4][4];
#pragma unroll
    for (int i = 0; i < 4; ++i)
#pragma unroll
        for (int j = 0; j < 4; ++j)
            acc[i][j] = f32x4{0.f, 0.f, 0.f, 0.f};

    // preload source nodes for the two A rows this thread stages
    int nodes[2][NR];
#pragma unroll
    for (int i = 0; i < 2; ++i) {
        int m = m0 + i * 32 + srow; m = (m < E) ? m : (E - 1);
        int entry = (ARITY == 0) ? m : sorted[m];
        if constexpr (ARITY == 0) nodes[i][0] = entry;
        else {
#pragma unroll
            for (int r = 0; r < NR; ++r) nodes[i][r] = eidx[r * E + entry];
        }
    }

    uint4 ra[2], rb[8];
    auto load_tile = [&](int k0) {
        const int slot_k = k0 >> 8;
        const int kin = k0 & 255;
#pragma unroll
        for (int i = 0; i < 2; ++i)
            ra[i] = *(const uint4*)(hb + nodes[i][slot_k] * D + kin + sc * 8);
#pragma unroll
        for (int j = 0; j < 8; ++j)
            rb[j] = *(const uint4*)(Wt + (j * 32 + srow) * KT + k0 + sc * 8);
    };

    load_tile(0);
    for (int k0 = 0; k0 < KT; k0 += BK) {
        __syncthreads();
#pragma unroll
        for (int i = 0; i < 2; ++i)
            *(uint4*)(smem + (i * 32 + srow) * LDSP + sc * 16) = ra[i];
#pragma unroll
        for (int j = 0; j < 8; ++j)
            *(uint4*)(smem + BOFF + (j * 32 + srow) * LDSP + sc * 16) = rb[j];
        __syncthreads();
        if (k0 + BK < KT) load_tile(k0 + BK);
#pragma unroll
        for (int ks = 0; ks < 2; ++ks) {
            const int koff = ks * 64 + (lane >> 4) * 16;
            bf16x8 af[4], bf[4];
#pragma unroll
            for (int mi = 0; mi < 4; ++mi)
                af[mi] = *(const bf16x8*)(smem + (mi * 16 + (lane & 15)) * LDSP + koff);
#pragma unroll
            for (int ni = 0; ni < 4; ++ni)
                bf[ni] = *(const bf16x8*)(smem + BOFF + (wn + ni * 16 + (lane & 15)) * LDSP + koff);
#pragma unroll
            for (int mi = 0; mi < 4; ++mi)
#pragma unroll
                for (int ni = 0; ni < 4; ++ni)
                    acc[mi][ni] = __builtin_amdgcn_mfma_f32_16x16x32_bf16(
                        af[mi], bf[ni], acc[mi][ni], 0, 0, 0);
        }
    }

    // epilogue: C row = mi*16 + (lane>>4)*4 + r ; col = wn + ni*16 + (lane&15)
    const int colb = wn + (lane & 15);
#pragma unroll
    for (int mi = 0; mi < 4; ++mi) {
        int mbase = m0 + mi * 16 + ((lane >> 4) << 2);
        if constexpr (ARITY == 0) {
#pragma unroll
            for (int r = 0; r < 4; ++r) {
                int m = mbase + r;
                if (m < E) {
#pragma unroll
                    for (int ni = 0; ni < 4; ++ni)
                        agg[m * D + colb + ni * 16] = acc[mi][ni][r];
                }
            }
        } else {
            int dst[4]; bool ok[4];
#pragma unroll
            for (int r = 0; r < 4; ++r) {
                int m = mbase + r; ok[r] = (m < E);
                int mm = ok[r] ? m : (E - 1);
                dst[r] = eidx[slot * E + sorted[mm]];
            }
            bool same = ok[0] && ok[1] && ok[2] && ok[3] &&
                        dst[0] == dst[1] && dst[1] == dst[2] && dst[2] == dst[3];
            if (same) {
#pragma unroll
                for (int ni = 0; ni < 4; ++ni) {
                    f32x4 a = acc[mi][ni];
                    atomicAdd(agg + dst[0] * D + colb + ni * 16,
                              (a[0] + a[1]) + (a[2] + a[3]));
                }
            } else {
#pragma unroll
                for (int r = 0; r < 4; ++r) {
                    if (ok[r]) {
#pragma unroll
                        for (int ni = 0; ni < 4; ++ni)
                            atomicAdd(agg + dst[r] * D + colb + ni * 16, acc[mi][ni][r]);
                    }
                }
            }
        }
    }
}

// ---------------- h = LN(relu(agg)) -> bf16 ----------------
__global__ __launch_bounds__(256)
void relu_ln_kernel(const float* __restrict__ agg, const float* __restrict__ g,
                    const float* __restrict__ b, u16* __restrict__ hb, int n) {
    int wid = threadIdx.x >> 6, lane = threadIdx.x & 63;
    int row = blockIdx.x * 4 + wid;
    if (row >= n) return;
    float4 v = *(const float4*)(agg + row * D + lane * 4);
    v.x = fmaxf(v.x, 0.f); v.y = fmaxf(v.y, 0.f);
    v.z = fmaxf(v.z, 0.f); v.w = fmaxf(v.w, 0.f);
    float s  = v.x + v.y + v.z + v.w;
    float s2 = v.x * v.x + v.y * v.y + v.z * v.z + v.w * v.w;
#pragma unroll
    for (int off = 1; off < 64; off <<= 1) {
        s  += __shfl_xor(s, off);
        s2 += __shfl_xor(s2, off);
    }
    float mu = s * 0.00390625f;
    float var = s2 * 0.00390625f - mu * mu;
    float rs = rsqrtf(var + 1e-5f);
    float4 gg = *(const float4*)(g + lane * 4);
    float4 bb = *(const float4*)(b + lane * 4);
    ushort4 o;
    o.x = f2b((v.x - mu) * rs * gg.x + bb.x);
    o.y = f2b((v.y - mu) * rs * gg.y + bb.y);
    o.z = f2b((v.z - mu) * rs * gg.z + bb.z);
    o.w = f2b((v.w - mu) * rs * gg.w + bb.w);
    *(ushort4*)(hb + row * D + lane * 4) = o;
}

// ---------------- head layers ----------------
__global__ __launch_bounds__(256)
void head_layer(const u16* __restrict__ hb, const int* __restrict__ tgt,
                const float* __restrict__ inf,
                const float* __restrict__ W, const float* __restrict__ bias,
                const float* __restrict__ g, const float* __restrict__ beta,
                float* __restrict__ out, int gather) {
    __shared__ float xr[256];
    __shared__ float sm1[4], sm2[4];
    int t = blockIdx.x, tid = threadIdx.x;
    if (gather) { int node = tgt[t]; xr[tid] = b2f(hb[node * D + tid]); }
    else        { xr[tid] = inf[t * D + tid]; }
    __syncthreads();
    float a = bias[tid];
#pragma unroll 8
    for (int k = 0; k < 256; ++k) a = fmaf(xr[k], W[k * 256 + tid], a);
    float s = a, s2 = a * a;
#pragma unroll
    for (int off = 1; off < 64; off <<= 1) {
        s  += __shfl_xor(s, off);
        s2 += __shfl_xor(s2, off);
    }
    int wid = tid >> 6, lane = tid & 63;
    if (lane == 0) { sm1[wid] = s; sm2[wid] = s2; }
    __syncthreads();
    s  = sm1[0] + sm1[1] + sm1[2] + sm1[3];
    s2 = sm2[0] + sm2[1] + sm2[2] + sm2[3];
    float mu = s * 0.00390625f;
    float var = s2 * 0.00390625f - mu * mu;
    float rs = rsqrtf(var + 1e-5f);
    float y = (a - mu) * rs * g[tid] + beta[tid];
    out[t * 256 + tid] = fmaxf(y, 0.f);
}

__global__ __launch_bounds__(256)
void head_out(const float* __restrict__ in, const float* __restrict__ ow,
              const float* __restrict__ ob, float* __restrict__ out, int T) {
    int wid = threadIdx.x >> 6, lane = threadIdx.x & 63;
    int t = blockIdx.x * 4 + wid;
    if (t >= T) return;
    float4 v = *(const float4*)(in + t * D + lane * 4);
    float4 w = *(const float4*)(ow + lane * 4);
    float s = v.x * w.x + v.y * w.y + v.z * w.z + v.w * w.w;
#pragma unroll
    for (int off = 1; off < 64; off <<= 1) s += __shfl_xor(s, off);
    if (lane == 0) out[t] = s + ob[0];
}

extern "C" void kernel_launch(void* const* d_in, const int* in_sizes, int n_in,
                              void* d_out, int out_size, void* d_ws, size_t ws_size,
                              hipStream_t stream) {
    (void)in_sizes; (void)n_in; (void)out_size; (void)ws_size;
    const int*   x      = (const int*)d_in[0];
    const int*   e2     = (const int*)d_in[2];
    const int*   e3     = (const int*)d_in[3];
    const int*   tgt    = (const int*)d_in[4];
    const float* emb    = (const float*)d_in[5];
    const float* W_root = (const float*)d_in[6];
    const float* W_e2   = (const float*)d_in[7];
    const float* W_e3   = (const float*)d_in[8];
    const float* ln_g   = (const float*)d_in[9];
    const float* ln_b   = (const float*)d_in[10];
    const float* reg_W  = (const float*)d_in[11];
    const float* reg_b  = (const float*)d_in[12];
    const float* rln_g  = (const float*)d_in[13];
    const float* rln_b  = (const float*)d_in[14];
    const float* out_W  = (const float*)d_in[15];
    const float* out_b  = (const float*)d_in[16];
    float* out = (float*)d_out;

    char* ws = (char*)d_ws;
    float* agg    = (float*)(ws);                     // 102,400,000 B
    int*   counts = (int*)  (ws);                     // aliases agg (dead before layer 0)
    u16*   hb     = (u16*)  (ws + 102400000);         //  51,200,000
    u16*   Wr     = (u16*)  (ws + 153600000);         //     524,288
    u16*   W2     = (u16*)  (ws + 154124288);         //   2,097,152
    u16*   W3     = (u16*)  (ws + 156221440);         //   4,718,592
    float* t0     = (float*)(ws + 160940032);         //   2,048,000
    float* t1     = (float*)(ws + 162988032);         //   2,048,000
    int*   sorted2= (int*)  (ws + 165036032);         //   2,400,000
    int*   sorted3= (int*)  (ws + 167436032);         //   2,400,000

    embed_kernel<<<N_NODES / 4, 256, 0, stream>>>(x, emb, hb, N_NODES);
    convert_wt<<<(NLAYER * 256 * 256 + 255) / 256, 256, 0, stream>>>(W_root, Wr, NLAYER * 256 * 256, 256, 256);
    convert_wt<<<(NLAYER * 512 * 512 + 255) / 256, 256, 0, stream>>>(W_e2, W2, NLAYER * 512 * 512, 512, 512);
    convert_wt<<<(NLAYER * 768 * 768 + 255) / 256, 256, 0, stream>>>(W_e3, W3, NLAYER * 768 * 768, 768, 768);

    // build destination-sorted edge permutations (one per edge-type x slot)
    zero_counts<<<(NSEG * NBINS + 255) / 256, 256, 0, stream>>>(counts);
    hist_kernel<<<(TOTENT + 255) / 256, 256, 0, stream>>>(e2, e3, counts);
    scan_kernel<<<NSEG, 1024, 0, stream>>>(counts);
    scatter_kernel<<<(TOTENT + 255) / 256, 256, 0, stream>>>(e2, e3, counts, sorted2, sorted3);

    const int g_root = (N_NODES + BM - 1) / BM;   // 1563
    const int g_e2   = (E2N + BM - 1) / BM;       // 4688
    const int g_e3   = (E3N + BM - 1) / BM;       // 3125
    for (int l = 0; l < NLAYER; ++l) {
        gemm_scatter<0><<<g_root, 256, 0, stream>>>(hb, Wr + (size_t)l * 256 * 256,
                                                    nullptr, nullptr, 0, agg, N_NODES);
        for (int s = 0; s < 2; ++s)
            gemm_scatter<2><<<g_e2, 256, 0, stream>>>(hb,
                W2 + (size_t)l * 512 * 512 + (size_t)s * 256 * 512,
                e2, sorted2 + s * E2N, s, agg, E2N);
        for (int s = 0; s < 3; ++s)
            gemm_scatter<3><<<g_e3, 256, 0, stream>>>(hb,
                W3 + (size_t)l * 768 * 768 + (size_t)s * 256 * 768,
                e3, sorted3 + s * E3N, s, agg, E3N);
        relu_ln_kernel<<<N_NODES / 4, 256, 0, stream>>>(agg, ln_g + l * D, ln_b + l * D, hb, N_NODES);
    }

    head_layer<<<TGT, 256, 0, stream>>>(hb, tgt, nullptr, reg_W, reg_b, rln_g, rln_b, t0, 1);
    head_layer<<<TGT, 256, 0, stream>>>(nullptr, nullptr, t0, reg_W + 65536, reg_b + 256, rln_g + 256, rln_b + 256, t1, 0);
    head_out<<<(TGT + 3) / 4, 256, 0, stream>>>(t1, out_W, out_b, out, TGT);
}

// Round 3
// 9369.899 us; speedup vs baseline: 1.0072x; 1.0072x over previous
//
#include <hip/hip_runtime.h>

typedef unsigned short u16;
typedef __bf16 bf16x8 __attribute__((ext_vector_type(8)));
typedef float f32x4 __attribute__((ext_vector_type(4)));

#define N_NODES 100000
#define D 256
#define NLAYER 4
#define E2N 300000
#define E3N 200000
#define TGT 2000

__device__ __forceinline__ u16 f2b(float f) {
    union { float f; unsigned u; } v; v.f = f;
    unsigned r = v.u + 0x7FFFu + ((v.u >> 16) & 1u);
    return (u16)(r >> 16);
}
__device__ __forceinline__ float b2f(u16 u) {
    union { unsigned u; float f; } v; v.u = ((unsigned)u) << 16; return v.f;
}

// ---------------- embedding gather ----------------
__global__ __launch_bounds__(256)
void embed_kernel(const int* __restrict__ x, const float* __restrict__ emb,
                  u16* __restrict__ hb, int n) {
    int wid = threadIdx.x >> 6, lane = threadIdx.x & 63;
    int row = blockIdx.x * 4 + wid;
    if (row >= n) return;
    int v = x[row];
    float4 f = *(const float4*)(emb + v * D + lane * 4);
    ushort4 o; o.x = f2b(f.x); o.y = f2b(f.y); o.z = f2b(f.z); o.w = f2b(f.w);
    *(ushort4*)(hb + row * D + lane * 4) = o;
}

// ---------------- W (L,K,N) f32 -> Wt (L,N,K) bf16 ----------------
__global__ __launch_bounds__(256)
void convert_wt(const float* __restrict__ W, u16* __restrict__ Wt,
                int total, int K, int N) {
    int idx = blockIdx.x * 256 + threadIdx.x;
    if (idx >= total) return;
    int kk = idx % K;
    int rem = idx / K;
    int nn = rem % N;
    int l  = rem / N;
    Wt[idx] = f2b(W[(l * K + kk) * N + nn]);
}

// ---------------- counting sort of (type,slot) edge entries by dest ----------------
#define NBINS 100000
#define NSEG 5              // e2:s0, e2:s1, e3:s0, e3:s1, e3:s2
#define TOTENT 1200000

__global__ __launch_bounds__(256)
void zero_counts(int* __restrict__ counts) {
    int i = blockIdx.x * 256 + threadIdx.x;
    if (i < NSEG * NBINS) counts[i] = 0;
}

__device__ __forceinline__ void decode_entry(int i, const int* e2, const int* e3,
                                             int& seg, int& key, int& e, int& is2) {
    if (i < 2 * E2N) {
        int s = i / E2N; e = i - s * E2N;
        seg = s; key = e2[s * E2N + e]; is2 = 1;
    } else {
        int j = i - 2 * E2N; int s = j / E3N; e = j - s * E3N;
        seg = 2 + s; key = e3[s * E3N + e]; is2 = 0;
    }
}

__global__ __launch_bounds__(256)
void hist_kernel(const int* __restrict__ e2, const int* __restrict__ e3,
                 int* __restrict__ counts) {
    int i = blockIdx.x * 256 + threadIdx.x;
    if (i >= TOTENT) return;
    int seg, key, e, is2;
    decode_entry(i, e2, e3, seg, key, e, is2);
    atomicAdd(counts + seg * NBINS + key, 1);
}

__global__ __launch_bounds__(1024)
void scan_kernel(int* __restrict__ counts) {   // grid = NSEG blocks
    __shared__ int ps[1024];
    int* seg = counts + blockIdx.x * NBINS;
    int t = threadIdx.x;
    const int C = (NBINS + 1023) / 1024;       // 98
    int b = t * C, en = b + C; if (en > NBINS) en = NBINS; if (b > NBINS) b = NBINS;
    int s = 0;
    for (int i = b; i < en; ++i) s += seg[i];
    ps[t] = s; __syncthreads();
    for (int off = 1; off < 1024; off <<= 1) {
        int v = ps[t];
        if (t >= off) v += ps[t - off];
        __syncthreads();
        ps[t] = v; __syncthreads();
    }
    int run = (t == 0) ? 0 : ps[t - 1];
    for (int i = b; i < en; ++i) { int c = seg[i]; seg[i] = run; run += c; }
}

__global__ __launch_bounds__(256)
void scatter_kernel(const int* __restrict__ e2, const int* __restrict__ e3,
                    int* __restrict__ counts, int* __restrict__ sorted2,
                    int* __restrict__ sorted3) {
    int i = blockIdx.x * 256 + threadIdx.x;
    if (i >= TOTENT) return;
    int seg, key, e, is2;
    decode_entry(i, e2, e3, seg, key, e, is2);
    int pos = atomicAdd(counts + seg * NBINS + key, 1);
    if (is2) sorted2[seg * E2N + pos] = e;
    else     sorted3[(seg - 2) * E3N + pos] = e;
}

// ---------------- fused gather-GEMM-sorted-merge-scatter ----------------
// One 256-col output slot per launch. BM=64, BN=256, K = arity*256.
// Edges processed in dest-sorted order; epilogue merges equal-dest runs in LDS
// and updates agg with plain RMW (interior dests are block-exclusive); only
// first/last run of each block (possible straddlers) use atomicAdd.
#define BM 64
#define BN 256
#define BK 64
#define LDSP 144
#define BOFF 9216          // 64*144
#define CP 260             // C-dump pitch in floats (bank-skewed)

template<int ARITY>
__global__ __launch_bounds__(256)
void gemm_scatter(const u16* __restrict__ hb, const u16* __restrict__ Wt,
                  const int* __restrict__ eidx, const int* __restrict__ sorted,
                  int slot, float* __restrict__ agg, int E) {
    constexpr int KT = (ARITY == 0 ? 1 : ARITY) * 256;
    constexpr int NR = (ARITY == 0 ? 1 : ARITY);
    constexpr int LDS_BYTES = (ARITY == 0) ? (64 + 256) * LDSP
                                           : (64 * CP * 4 + 256);  // 66816
    __shared__ __align__(16) char smem[LDS_BYTES];

    const int m0 = blockIdx.x * BM;
    const int tid = threadIdx.x;
    const int lane = tid & 63;
    const int wid = tid >> 6;
    const int wn = wid * 64;
    const int srow = tid >> 3;   // 0..31
    const int sc   = tid & 7;    // 16B chunk

    f32x4 acc[4][4];
#pragma unroll
    for (int i = 0; i < 4; ++i)
#pragma unroll
        for (int j = 0; j < 4; ++j)
            acc[i][j] = f32x4{0.f, 0.f, 0.f, 0.f};

    // preload source nodes for the two A rows this thread stages
    int nodes[2][NR];
#pragma unroll
    for (int i = 0; i < 2; ++i) {
        int m = m0 + i * 32 + srow; m = (m < E) ? m : (E - 1);
        int entry = (ARITY == 0) ? m : sorted[m];
        if constexpr (ARITY == 0) nodes[i][0] = entry;
        else {
#pragma unroll
            for (int r = 0; r < NR; ++r) nodes[i][r] = eidx[r * E + entry];
        }
    }

    uint4 ra[2], rb[8];
    auto load_tile = [&](int k0) {
        const int slot_k = k0 >> 8;
        const int kin = k0 & 255;
#pragma unroll
        for (int i = 0; i < 2; ++i)
            ra[i] = *(const uint4*)(hb + nodes[i][slot_k] * D + kin + sc * 8);
#pragma unroll
        for (int j = 0; j < 8; ++j)
            rb[j] = *(const uint4*)(Wt + (j * 32 + srow) * KT + k0 + sc * 8);
    };

    load_tile(0);
    for (int k0 = 0; k0 < KT; k0 += BK) {
        __syncthreads();
#pragma unroll
        for (int i = 0; i < 2; ++i)
            *(uint4*)(smem + (i * 32 + srow) * LDSP + sc * 16) = ra[i];
#pragma unroll
        for (int j = 0; j < 8; ++j)
            *(uint4*)(smem + BOFF + (j * 32 + srow) * LDSP + sc * 16) = rb[j];
        __syncthreads();
        if (k0 + BK < KT) load_tile(k0 + BK);
#pragma unroll
        for (int ks = 0; ks < 2; ++ks) {
            const int koff = ks * 64 + (lane >> 4) * 16;
            bf16x8 af[4], bf[4];
#pragma unroll
            for (int mi = 0; mi < 4; ++mi)
                af[mi] = *(const bf16x8*)(smem + (mi * 16 + (lane & 15)) * LDSP + koff);
#pragma unroll
            for (int ni = 0; ni < 4; ++ni)
                bf[ni] = *(const bf16x8*)(smem + BOFF + (wn + ni * 16 + (lane & 15)) * LDSP + koff);
#pragma unroll
            for (int mi = 0; mi < 4; ++mi)
#pragma unroll
                for (int ni = 0; ni < 4; ++ni)
                    acc[mi][ni] = __builtin_amdgcn_mfma_f32_16x16x32_bf16(
                        af[mi], bf[ni], acc[mi][ni], 0, 0, 0);
        }
    }

    if constexpr (ARITY == 0) {
        // root: direct store. C row = mi*16+(lane>>4)*4+r ; col = wn+ni*16+(lane&15)
        const int colb = wn + (lane & 15);
#pragma unroll
        for (int mi = 0; mi < 4; ++mi) {
            int mbase = m0 + mi * 16 + ((lane >> 4) << 2);
#pragma unroll
            for (int r = 0; r < 4; ++r) {
                int m = mbase + r;
                if (m < E) {
#pragma unroll
                    for (int ni = 0; ni < 4; ++ni)
                        agg[m * D + colb + ni * 16] = acc[mi][ni][r];
                }
            }
        }
    } else {
        // dump C tile to LDS, then per-column segmented merge over sorted dests
        __syncthreads();   // all waves done reading staging LDS
        float* cl = (float*)smem;
        int* dsh = (int*)(smem + 64 * CP * 4);
#pragma unroll
        for (int mi = 0; mi < 4; ++mi) {
            int rbase = mi * 16 + ((lane >> 4) << 2);
            int cb = wn + (lane & 15);
#pragma unroll
            for (int ni = 0; ni < 4; ++ni) {
#pragma unroll
                for (int r = 0; r < 4; ++r)
                    cl[(rbase + r) * CP + cb + ni * 16] = acc[mi][ni][r];
            }
        }
        if (tid < 64) {
            int m = m0 + tid;
            dsh[tid] = (m < E) ? eidx[slot * E + sorted[m]] : -1;
        }
        __syncthreads();

        const int col = wn + lane;   // wait: lane is 0..63, wn = wid*64 -> col 0..255
        float run = 0.f;
        int d = dsh[0];
        bool isfirst = true;
#pragma unroll
        for (int row = 0; row < 64; ++row) {
            run += cl[row * CP + col];
            int dn = (row < 63) ? dsh[row + 1] : -2;
            if (dn != d) {
                if (d >= 0) {
                    float* p = agg + d * D + col;
                    if (isfirst || row == 63) atomicAdd(p, run);
                    else *p += run;           // interior dest: block-exclusive
                }
                run = 0.f; d = dn; isfirst = false;
            }
        }
    }
}

// ---------------- h = LN(relu(agg)) -> bf16 ----------------
__global__ __launch_bounds__(256)
void relu_ln_kernel(const float* __restrict__ agg, const float* __restrict__ g,
                    const float* __restrict__ b, u16* __restrict__ hb, int n) {
    int wid = threadIdx.x >> 6, lane = threadIdx.x & 63;
    int row = blockIdx.x * 4 + wid;
    if (row >= n) return;
    float4 v = *(const float4*)(agg + row * D + lane * 4);
    v.x = fmaxf(v.x, 0.f); v.y = fmaxf(v.y, 0.f);
    v.z = fmaxf(v.z, 0.f); v.w = fmaxf(v.w, 0.f);
    float s  = v.x + v.y + v.z + v.w;
    float s2 = v.x * v.x + v.y * v.y + v.z * v.z + v.w * v.w;
#pragma unroll
    for (int off = 1; off < 64; off <<= 1) {
        s  += __shfl_xor(s, off);
        s2 += __shfl_xor(s2, off);
    }
    float mu = s * 0.00390625f;
    float var = s2 * 0.00390625f - mu * mu;
    float rs = rsqrtf(var + 1e-5f);
    float4 gg = *(const float4*)(g + lane * 4);
    float4 bb = *(const float4*)(b + lane * 4);
    ushort4 o;
    o.x = f2b((v.x - mu) * rs * gg.x + bb.x);
    o.y = f2b((v.y - mu) * rs * gg.y + bb.y);
    o.z = f2b((v.z - mu) * rs * gg.z + bb.z);
    o.w = f2b((v.w - mu) * rs * gg.w + bb.w);
    *(ushort4*)(hb + row * D + lane * 4) = o;
}

// ---------------- head layers ----------------
__global__ __launch_bounds__(256)
void head_layer(const u16* __restrict__ hb, const int* __restrict__ tgt,
                const float* __restrict__ inf,
                const float* __restrict__ W, const float* __restrict__ bias,
                const float* __restrict__ g, const float* __restrict__ beta,
                float* __restrict__ out, int gather) {
    __shared__ float xr[256];
    __shared__ float sm1[4], sm2[4];
    int t = blockIdx.x, tid = threadIdx.x;
    if (gather) { int node = tgt[t]; xr[tid] = b2f(hb[node * D + tid]); }
    else        { xr[tid] = inf[t * D + tid]; }
    __syncthreads();
    float a = bias[tid];
#pragma unroll 8
    for (int k = 0; k < 256; ++k) a = fmaf(xr[k], W[k * 256 + tid], a);
    float s = a, s2 = a * a;
#pragma unroll
    for (int off = 1; off < 64; off <<= 1) {
        s  += __shfl_xor(s, off);
        s2 += __shfl_xor(s2, off);
    }
    int wid = tid >> 6, lane = tid & 63;
    if (lane == 0) { sm1[wid] = s; sm2[wid] = s2; }
    __syncthreads();
    s  = sm1[0] + sm1[1] + sm1[2] + sm1[3];
    s2 = sm2[0] + sm2[1] + sm2[2] + sm2[3];
    float mu = s * 0.00390625f;
    float var = s2 * 0.00390625f - mu * mu;
    float rs = rsqrtf(var + 1e-5f);
    float y = (a - mu) * rs * g[tid] + beta[tid];
    out[t * 256 + tid] = fmaxf(y, 0.f);
}

__global__ __launch_bounds__(256)
void head_out(const float* __restrict__ in, const float* __restrict__ ow,
              const float* __restrict__ ob, float* __restrict__ out, int T) {
    int wid = threadIdx.x >> 6, lane = threadIdx.x & 63;
    int t = blockIdx.x * 4 + wid;
    if (t >= T) return;
    float4 v = *(const float4*)(in + t * D + lane * 4);
    float4 w = *(const float4*)(ow + lane * 4);
    float s = v.x * w.x + v.y * w.y + v.z * w.z + v.w * w.w;
#pragma unroll
    for (int off = 1; off < 64; off <<= 1) s += __shfl_xor(s, off);
    if (lane == 0) out[t] = s + ob[0];
}

extern "C" void kernel_launch(void* const* d_in, const int* in_sizes, int n_in,
                              void* d_out, int out_size, void* d_ws, size_t ws_size,
                              hipStream_t stream) {
    (void)in_sizes; (void)n_in; (void)out_size; (void)ws_size;
    const int*   x      = (const int*)d_in[0];
    const int*   e2     = (const int*)d_in[2];
    const int*   e3     = (const int*)d_in[3];
    const int*   tgt    = (const int*)d_in[4];
    const float* emb    = (const float*)d_in[5];
    const float* W_root = (const float*)d_in[6];
    const float* W_e2   = (const float*)d_in[7];
    const float* W_e3   = (const float*)d_in[8];
    const float* ln_g   = (const float*)d_in[9];
    const float* ln_b   = (const float*)d_in[10];
    const float* reg_W  = (const float*)d_in[11];
    const float* reg_b  = (const float*)d_in[12];
    const float* rln_g  = (const float*)d_in[13];
    const float* rln_b  = (const float*)d_in[14];
    const float* out_W  = (const float*)d_in[15];
    const float* out_b  = (const float*)d_in[16];
    float* out = (float*)d_out;

    char* ws = (char*)d_ws;
    float* agg    = (float*)(ws);                     // 102,400,000 B
    int*   counts = (int*)  (ws);                     // aliases agg (dead before layer 0)
    u16*   hb     = (u16*)  (ws + 102400000);         //  51,200,000
    u16*   Wr     = (u16*)  (ws + 153600000);         //     524,288
    u16*   W2     = (u16*)  (ws + 154124288);         //   2,097,152
    u16*   W3     = (u16*)  (ws + 156221440);         //   4,718,592
    float* t0     = (float*)(ws + 160940032);         //   2,048,000
    float* t1     = (float*)(ws + 162988032);         //   2,048,000
    int*   sorted2= (int*)  (ws + 165036032);         //   2,400,000
    int*   sorted3= (int*)  (ws + 167436032);         //   2,400,000

    embed_kernel<<<N_NODES / 4, 256, 0, stream>>>(x, emb, hb, N_NODES);
    convert_wt<<<(NLAYER * 256 * 256 + 255) / 256, 256, 0, stream>>>(W_root, Wr, NLAYER * 256 * 256, 256, 256);
    convert_wt<<<(NLAYER * 512 * 512 + 255) / 256, 256, 0, stream>>>(W_e2, W2, NLAYER * 512 * 512, 512, 512);
    convert_wt<<<(NLAYER * 768 * 768 + 255) / 256, 256, 0, stream>>>(W_e3, W3, NLAYER * 768 * 768, 768, 768);

    // build destination-sorted edge permutations (one per edge-type x slot)
    zero_counts<<<(NSEG * NBINS + 255) / 256, 256, 0, stream>>>(counts);
    hist_kernel<<<(TOTENT + 255) / 256, 256, 0, stream>>>(e2, e3, counts);
    scan_kernel<<<NSEG, 1024, 0, stream>>>(counts);
    scatter_kernel<<<(TOTENT + 255) / 256, 256, 0, stream>>>(e2, e3, counts, sorted2, sorted3);

    const int g_root = (N_NODES + BM - 1) / BM;   // 1563
    const int g_e2   = (E2N + BM - 1) / BM;       // 4688
    const int g_e3   = (E3N + BM - 1) / BM;       // 3125
    for (int l = 0; l < NLAYER; ++l) {
        gemm_scatter<0><<<g_root, 256, 0, stream>>>(hb, Wr + (size_t)l * 256 * 256,
                                                    nullptr, nullptr, 0, agg, N_NODES);
        for (int s = 0; s < 2; ++s)
            gemm_scatter<2><<<g_e2, 256, 0, stream>>>(hb,
                W2 + (size_t)l * 512 * 512 + (size_t)s * 256 * 512,
                e2, sorted2 + s * E2N, s, agg, E2N);
        for (int s = 0; s < 3; ++s)
            gemm_scatter<3><<<g_e3, 256, 0, stream>>>(hb,
                W3 + (size_t)l * 768 * 768 + (size_t)s * 256 * 768,
                e3, sorted3 + s * E3N, s, agg, E3N);
        relu_ln_kernel<<<N_NODES / 4, 256, 0, stream>>>(agg, ln_g + l * D, ln_b + l * D, hb, N_NODES);
    }

    head_layer<<<TGT, 256, 0, stream>>>(hb, tgt, nullptr, reg_W, reg_b, rln_g, rln_b, t0, 1);
    head_layer<<<TGT, 256, 0, stream>>>(nullptr, nullptr, t0, reg_W + 65536, reg_b + 256, rln_g + 256, rln_b + 256, t1, 0);
    head_out<<<(TGT + 3) / 4, 256, 0, stream>>>(t1, out_W, out_b, out, TGT);
}